// Round 6
// baseline (703.225 us; speedup 1.0000x reference)
//
#include <hip/hip_runtime.h>
#include <hip/hip_bf16.h>
#include <stdint.h>
#include <math.h>

#define NPTS 2048
#define BSZ 8
#define KNN 16
#define MROWS (BSZ * NPTS)   // 16384

typedef __attribute__((ext_vector_type(8))) short bf16x8;
typedef __attribute__((ext_vector_type(4))) float f32x4;

__device__ __forceinline__ unsigned short f2bf(float f) {
    __hip_bfloat16 h = __float2bfloat16(f);
    return *(unsigned short*)&h;
}
__device__ __forceinline__ float bf2f(unsigned short u) {
    return __uint_as_float(((unsigned)u) << 16);
}

// ---------- sorting primitives on (f32 dist, u32 idx) pairs ----------
#define CASF(ad, ai, bd, bi) { \
    const bool sw_ = (bd) < (ad); \
    const float d0_ = sw_ ? (bd) : (ad); const float d1_ = sw_ ? (ad) : (bd); \
    const unsigned i0_ = sw_ ? (bi) : (ai); const unsigned i1_ = sw_ ? (ai) : (bi); \
    (ad) = d0_; (bd) = d1_; (ai) = i0_; (bi) = i1_; }

__device__ __forceinline__ void sort16(float d[16], unsigned ii[16]) {
    #pragma unroll
    for (int k = 2; k <= 16; k <<= 1) {
        #pragma unroll
        for (int j = k >> 1; j > 0; j >>= 1) {
            #pragma unroll
            for (int i = 0; i < 16; ++i) {
                const int l = i ^ j;
                if (l > i) {
                    if ((i & k) == 0) { CASF(d[i], ii[i], d[l], ii[l]); }
                    else              { CASF(d[l], ii[l], d[i], ii[i]); }
                }
            }
        }
    }
}

__device__ __forceinline__ void clean16(float d[16], unsigned ii[16]) {
    #pragma unroll
    for (int j = 8; j > 0; j >>= 1) {
        #pragma unroll
        for (int i = 0; i < 16; ++i) {
            const int l = i ^ j;
            if (l > i) { CASF(d[i], ii[i], d[l], ii[l]); }
        }
    }
}

// ---------- KNN + covariance ----------
// 4096 blocks x 256 threads; one query per wave.
// Phase 1 per lane: 2 chunks of 16 candidates, sort16 + bitonic merge-keep-16.
// Phase 2: 6 cross-lane bitonic merge rounds -> wave-global top-16.
__global__ __launch_bounds__(256, 2)
void knn_cov_kernel(const float* __restrict__ x, const int* __restrict__ mask,
                    int* __restrict__ idx_out, float* __restrict__ h0)
{
    __shared__ float4 cand[NPTS];
    const int tid  = threadIdx.x;
    const int wave = tid >> 6;
    const int lane = tid & 63;
    const int b = blockIdx.x >> 9;
    const int q = ((blockIdx.x & 511) << 2) + wave;
    const float* xb = x + (size_t)b * 3 * NPTS;
    const int*   mb = mask + b * NPTS;

    for (int m = tid; m < NPTS; m += 256) {
        float px = xb[m], py = xb[NPTS + m], pz = xb[2 * NPTS + m];
        float sq = px * px + py * py + pz * pz;
        if (mb[m] != 1) sq = INFINITY;
        cand[m] = make_float4(px, py, pz, sq);
    }
    __syncthreads();

    const float4 qc = cand[q];
    const float qx = qc.x, qy = qc.y, qz = qc.z;
    const float sqn = qx * qx + qy * qy + qz * qz;

    float ld[16]; unsigned li[16];
    #pragma unroll
    for (int i = 0; i < 16; ++i) { ld[i] = INFINITY; li[i] = 0u; }

    #pragma unroll 1
    for (int ch = 0; ch < 2; ++ch) {
        float cd[16]; unsigned ci[16];
        #pragma unroll
        for (int t = 0; t < 16; ++t) {
            const int m = (ch * 16 + t) * 64 + lane;
            const float4 c = cand[m];
            cd[t] = fmaf(-2.f, qx * c.x + qy * c.y + qz * c.z, sqn + c.w);
            ci[t] = (unsigned)m;
        }
        sort16(cd, ci);
        float md[16]; unsigned mi[16];
        #pragma unroll
        for (int i = 0; i < 16; ++i) {
            const float pd = cd[15 - i]; const unsigned pi = ci[15 - i];
            const bool t = pd < ld[i];
            md[i] = t ? pd : ld[i]; mi[i] = t ? pi : li[i];
        }
        clean16(md, mi);
        #pragma unroll
        for (int i = 0; i < 16; ++i) { ld[i] = md[i]; li[i] = mi[i]; }
    }

    #pragma unroll 1
    for (int p = 1; p <= 32; p <<= 1) {
        float md[16]; unsigned mi[16];
        #pragma unroll
        for (int i = 0; i < 16; ++i) {
            const float pd = __shfl_xor(ld[15 - i], p, 64);
            const unsigned pi = (unsigned)__shfl_xor((int)li[15 - i], p, 64);
            const bool t = pd < ld[i];
            md[i] = t ? pd : ld[i]; mi[i] = t ? pi : li[i];
        }
        clean16(md, mi);
        #pragma unroll
        for (int i = 0; i < 16; ++i) { ld[i] = md[i]; li[i] = mi[i]; }
    }

    const int gq = b * NPTS + q;
    if (lane < KNN)
        idx_out[gq * KNN + lane] = b * NPTS + (int)li[lane];

    const int ml = (int)li[lane & 15];
    const float4 nb = cand[ml];
    float sx = nb.x, sy = nb.y, sz = nb.z;
    #pragma unroll
    for (int m = 1; m < 16; m <<= 1) {
        sx += __shfl_xor(sx, m, 64); sy += __shfl_xor(sy, m, 64); sz += __shfl_xor(sz, m, 64);
    }
    const float mx = sx * 0.0625f, my = sy * 0.0625f, mz = sz * 0.0625f;
    const float cx = nb.x - mx, cy = nb.y - my, cz = nb.z - mz;
    float xx = cx * cx, xy = cx * cy, xz = cx * cz;
    float yy = cy * cy, yz = cy * cz, zz = cz * cz;
    #pragma unroll
    for (int m = 1; m < 16; m <<= 1) {
        xx += __shfl_xor(xx, m, 64); xy += __shfl_xor(xy, m, 64); xz += __shfl_xor(xz, m, 64);
        yy += __shfl_xor(yy, m, 64); yz += __shfl_xor(yz, m, 64); zz += __shfl_xor(zz, m, 64);
    }
    if (lane == 0) {
        float* o = h0 + (size_t)gq * 12;
        o[0] = qx; o[1] = qy; o[2] = qz;
        o[3] = xx; o[4] = xy; o[5] = xz;
        o[6] = xy; o[7] = yy; o[8] = yz;
        o[9] = xz; o[10] = yz; o[11] = zz;
    }
}

// ---------- fp32 GEMM with fused stats output (+optional folded BN on X) ----------
// BNX: computes scale/shift from prev layer's psum chunks (K=64, 256 chunks).
// Always writes per-block psum/psumsq chunk (chunk id = blockIdx.x, 256 chunks).
template<bool BNX>
__global__ __launch_bounds__(256)
void gemm_bias_kernel(const float* __restrict__ X, const float* __restrict__ W,
                      const float* __restrict__ bias,
                      const float* __restrict__ bps, const float* __restrict__ bpss,
                      const float* __restrict__ bg, const float* __restrict__ bbe,
                      float* __restrict__ Y,
                      float* __restrict__ ops, float* __restrict__ opss,
                      int K, int C)
{
    __shared__ float Xs[16][65];
    __shared__ float Ws[16][65];
    __shared__ float s_sc[64], s_sh[64];
    __shared__ float rs[16][64], rss[16][64];
    const int tid = threadIdx.x;

    if (BNX) {
        const int c = tid & 63, part = tid >> 6;
        float s = 0.f, ss = 0.f;
        for (int i = part * 64; i < part * 64 + 64; ++i) {
            s += bps[(size_t)i * 64 + c];
            ss += bpss[(size_t)i * 64 + c];
        }
        rs[part][c] = s; rss[part][c] = ss;
        __syncthreads();
        if (tid < 64) {
            const float S  = rs[0][tid] + rs[1][tid] + rs[2][tid] + rs[3][tid];
            const float SS = rss[0][tid] + rss[1][tid] + rss[2][tid] + rss[3][tid];
            const float invM = 1.f / (float)MROWS;
            const float mean = S * invM;
            const float var = fmaxf(SS * invM - mean * mean, 0.f);
            const float sc = bg[tid] * rsqrtf(var + 1e-5f);
            s_sc[tid] = sc;
            s_sh[tid] = bbe[tid] - mean * sc;
        }
        __syncthreads();
    }

    const int bm = blockIdx.x << 6;
    const int bn = blockIdx.y << 6;
    const int ty = tid >> 4, tx = tid & 15;
    float acc[4][4] = {};
    for (int k0 = 0; k0 < K; k0 += 16) {
        #pragma unroll
        for (int e = tid; e < 1024; e += 256) {
            const int m = e >> 4, k = e & 15;
            float v = 0.f;
            if (k0 + k < K) {
                v = X[(size_t)(bm + m) * K + k0 + k];
                if (BNX) v = fmaxf(0.f, fmaf(v, s_sc[k0 + k], s_sh[k0 + k]));
            }
            Xs[k][m] = v;
        }
        #pragma unroll
        for (int e = tid; e < 1024; e += 256) {
            const int k = e >> 6, n = e & 63;
            Ws[k][n] = (k0 + k < K) ? W[(size_t)(k0 + k) * C + bn + n] : 0.f;
        }
        __syncthreads();
        #pragma unroll
        for (int k = 0; k < 16; ++k) {
            float a[4], bb[4];
            #pragma unroll
            for (int i = 0; i < 4; ++i) a[i] = Xs[k][ty * 4 + i];
            #pragma unroll
            for (int j = 0; j < 4; ++j) bb[j] = Ws[k][tx * 4 + j];
            #pragma unroll
            for (int i = 0; i < 4; ++i)
                #pragma unroll
                for (int j = 0; j < 4; ++j)
                    acc[i][j] = fmaf(a[i], bb[j], acc[i][j]);
        }
        __syncthreads();
    }

    float se[4] = {0.f, 0.f, 0.f, 0.f}, sse[4] = {0.f, 0.f, 0.f, 0.f};
    #pragma unroll
    for (int i = 0; i < 4; ++i) {
        const int r = bm + ty * 4 + i;
        #pragma unroll
        for (int j = 0; j < 4; ++j) {
            const int ccol = bn + tx * 4 + j;
            const float yv = acc[i][j] + bias[ccol];
            Y[(size_t)r * C + ccol] = yv;
            se[j] += yv; sse[j] = fmaf(yv, yv, sse[j]);
        }
    }
    #pragma unroll
    for (int j = 0; j < 4; ++j) { rs[ty][tx * 4 + j] = se[j]; rss[ty][tx * 4 + j] = sse[j]; }
    __syncthreads();
    if (tid < 64) {
        float S = 0.f, SS = 0.f;
        #pragma unroll
        for (int r2 = 0; r2 < 16; ++r2) { S += rs[r2][tid]; SS += rss[r2][tid]; }
        ops[(size_t)blockIdx.x * C + bn + tid] = S;
        opss[(size_t)blockIdx.x * C + bn + tid] = SS;
    }
}

// ---------- w_gl2 -> split bf16 transposed [n][k]: hi + lo(residual) ----------
__global__ void cvt_wgl2_kernel(const float* __restrict__ w,
                                unsigned short* __restrict__ wT_hi,
                                unsigned short* __restrict__ wT_lo)
{
    const int t = blockIdx.x * 256 + threadIdx.x;   // t = n*128 + k
    const int n = t >> 7, k = t & 127;
    const float v = w[(size_t)k * 1024 + n];
    const unsigned short hi = f2bf(v);
    wT_hi[t] = hi;
    wT_lo[t] = f2bf(v - bf2f(hi));
}

// ---------- gl2 MFMA GEMM (split-bf16, 3 passes) + fused psum chunks ----------
// grid (128, 8), 256 threads = 4 waves (2x2), 64x64 per wave.
__global__ __launch_bounds__(256)
void gemm_gl2_mfma(const unsigned short* __restrict__ Ahi, const unsigned short* __restrict__ Alo,
                   const unsigned short* __restrict__ Whi, const unsigned short* __restrict__ Wlo,
                   const float* __restrict__ bias, float* __restrict__ Y,
                   float* __restrict__ ops, float* __restrict__ opss)
{
    __shared__ float ps[2][128], pss2[2][128];
    const int wave = threadIdx.x >> 6, lane = threadIdx.x & 63;
    const int wm = wave >> 1, wn = wave & 1;
    const int bm = blockIdx.x * 128 + wm * 64;
    const int bn = blockIdx.y * 128 + wn * 64;
    const int lrow = lane & 15;
    const int lk = (lane >> 4) * 8;
    f32x4 acc[4][4] = {};
    #pragma unroll
    for (int ks = 0; ks < 4; ++ks) {
        const int k0 = ks * 32 + lk;
        bf16x8 ah[4], al[4], bh[4], bl[4];
        #pragma unroll
        for (int mf = 0; mf < 4; ++mf) {
            const size_t off = (size_t)(bm + mf * 16 + lrow) * 128 + k0;
            ah[mf] = *(const bf16x8*)(Ahi + off);
            al[mf] = *(const bf16x8*)(Alo + off);
        }
        #pragma unroll
        for (int nf = 0; nf < 4; ++nf) {
            const size_t off = (size_t)(bn + nf * 16 + lrow) * 128 + k0;
            bh[nf] = *(const bf16x8*)(Whi + off);
            bl[nf] = *(const bf16x8*)(Wlo + off);
        }
        #pragma unroll
        for (int mf = 0; mf < 4; ++mf)
            #pragma unroll
            for (int nf = 0; nf < 4; ++nf) {
                acc[mf][nf] = __builtin_amdgcn_mfma_f32_16x16x32_bf16(ah[mf], bh[nf], acc[mf][nf], 0, 0, 0);
                acc[mf][nf] = __builtin_amdgcn_mfma_f32_16x16x32_bf16(ah[mf], bl[nf], acc[mf][nf], 0, 0, 0);
                acc[mf][nf] = __builtin_amdgcn_mfma_f32_16x16x32_bf16(al[mf], bh[nf], acc[mf][nf], 0, 0, 0);
            }
    }
    const int r0 = (lane >> 4) * 4, cc = lane & 15;
    float s[4] = {0.f, 0.f, 0.f, 0.f}, sq2[4] = {0.f, 0.f, 0.f, 0.f};
    #pragma unroll
    for (int mf = 0; mf < 4; ++mf) {
        const int row = bm + mf * 16 + r0;
        #pragma unroll
        for (int nf = 0; nf < 4; ++nf) {
            const int col = bn + nf * 16 + cc;
            const float bv = bias[col];
            #pragma unroll
            for (int r = 0; r < 4; ++r) {
                const float yv = acc[mf][nf][r] + bv;
                Y[(size_t)(row + r) * 1024 + col] = yv;
                s[nf] += yv; sq2[nf] = fmaf(yv, yv, sq2[nf]);
            }
        }
    }
    #pragma unroll
    for (int nf = 0; nf < 4; ++nf) {
        #pragma unroll
        for (int off = 16; off < 64; off <<= 1) {
            s[nf]   += __shfl_xor(s[nf], off, 64);
            sq2[nf] += __shfl_xor(sq2[nf], off, 64);
        }
    }
    if (lane < 16) {
        #pragma unroll
        for (int nf = 0; nf < 4; ++nf) {
            ps[wm][wn * 64 + nf * 16 + lane] = s[nf];
            pss2[wm][wn * 64 + nf * 16 + lane] = sq2[nf];
        }
    }
    __syncthreads();
    if (threadIdx.x < 128) {
        const size_t o = (size_t)blockIdx.x * 1024 + blockIdx.y * 128 + threadIdx.x;
        ops[o]  = ps[0][threadIdx.x] + ps[1][threadIdx.x];
        opss[o] = pss2[0][threadIdx.x] + pss2[1][threadIdx.x];
    }
}

// ---------- stats final (gl2 only): 128 chunks, C=1024 ----------
__global__ void stats_final_kernel(const float* __restrict__ psum, const float* __restrict__ psumsq,
                                   const float* __restrict__ g, const float* __restrict__ be,
                                   float* __restrict__ scale, float* __restrict__ shift,
                                   int C, int nchunks)
{
    const int c = blockIdx.x * 256 + threadIdx.x;
    if (c >= C) return;
    float s = 0.f, ss = 0.f;
    for (int i = 0; i < nchunks; ++i) { s += psum[(size_t)i * C + c]; ss += psumsq[(size_t)i * C + c]; }
    const float invM = 1.f / (float)MROWS;
    const float mean = s * invM;
    const float var = fmaxf(ss * invM - mean * mean, 0.f);
    const float sc = g[c] * rsqrtf(var + 1e-5f);
    scale[c] = sc;
    shift[c] = be[c] - mean * sc;
}

// ---------- gather-max + folded BN-final, 64 ch ----------
// grid 256 blocks x 64 rows (16 rows in flight, 4 iters)
__global__ __launch_bounds__(256)
void gathermax_bn64(const float* __restrict__ Hin, const int* __restrict__ idxmat,
                    const float* __restrict__ bps, const float* __restrict__ bpss,
                    const float* __restrict__ bg, const float* __restrict__ bbe,
                    float* __restrict__ Z)
{
    __shared__ float s_sc[64], s_sh[64];
    __shared__ float red[4][64], red2[4][64];
    const int tid = threadIdx.x;
    {
        const int c = tid & 63, part = tid >> 6;
        float s = 0.f, ss = 0.f;
        for (int i = part * 64; i < part * 64 + 64; ++i) {
            s += bps[(size_t)i * 64 + c]; ss += bpss[(size_t)i * 64 + c];
        }
        red[part][c] = s; red2[part][c] = ss;
        __syncthreads();
        if (tid < 64) {
            const float S  = red[0][tid] + red[1][tid] + red[2][tid] + red[3][tid];
            const float SS = red2[0][tid] + red2[1][tid] + red2[2][tid] + red2[3][tid];
            const float invM = 1.f / (float)MROWS;
            const float mean = S * invM;
            const float var = fmaxf(SS * invM - mean * mean, 0.f);
            const float sc = bg[tid] * rsqrtf(var + 1e-5f);
            s_sc[tid] = sc; s_sh[tid] = bbe[tid] - mean * sc;
        }
        __syncthreads();
    }
    const int c4 = tid & 15, rr = tid >> 4;
    const float4 sc = *(const float4*)&s_sc[c4 * 4];
    const float4 sh = *(const float4*)&s_sh[c4 * 4];
    #pragma unroll
    for (int it = 0; it < 4; ++it) {
        const int row = (blockIdx.x << 6) + (it << 4) + rr;
        const int* ip = idxmat + (size_t)row * KNN;
        float4 m = {0.f, 0.f, 0.f, 0.f};
        #pragma unroll
        for (int k = 0; k < KNN; ++k) {
            const int j = ip[k];
            const float4 v = *(const float4*)(Hin + (size_t)j * 64 + c4 * 4);
            m.x = fmaxf(m.x, fmaf(v.x, sc.x, sh.x));
            m.y = fmaxf(m.y, fmaf(v.y, sc.y, sh.y));
            m.z = fmaxf(m.z, fmaf(v.z, sc.z, sh.z));
            m.w = fmaxf(m.w, fmaf(v.w, sc.w, sh.w));
        }
        ((float4*)(Z + (size_t)row * 64))[c4] = m;
    }
}

// ---------- gather-max + folded BN-final, 128 ch, split-bf16 out ----------
// grid 256 blocks x 64 rows (8 rows in flight, 8 iters)
__global__ __launch_bounds__(256)
void gathermax_bn128_split(const float* __restrict__ Hin, const int* __restrict__ idxmat,
                           const float* __restrict__ bps, const float* __restrict__ bpss,
                           const float* __restrict__ bg, const float* __restrict__ bbe,
                           unsigned short* __restrict__ Zhi, unsigned short* __restrict__ Zlo)
{
    __shared__ float s_sc[128], s_sh[128];
    __shared__ float red[2][128], red2[2][128];
    const int tid = threadIdx.x;
    {
        const int c = tid & 127, part = tid >> 7;
        float s = 0.f, ss = 0.f;
        for (int i = part * 128; i < part * 128 + 128; ++i) {
            s += bps[(size_t)i * 128 + c]; ss += bpss[(size_t)i * 128 + c];
        }
        red[part][c] = s; red2[part][c] = ss;
        __syncthreads();
        if (tid < 128) {
            const float S  = red[0][tid] + red[1][tid];
            const float SS = red2[0][tid] + red2[1][tid];
            const float invM = 1.f / (float)MROWS;
            const float mean = S * invM;
            const float var = fmaxf(SS * invM - mean * mean, 0.f);
            const float sc = bg[tid] * rsqrtf(var + 1e-5f);
            s_sc[tid] = sc; s_sh[tid] = bbe[tid] - mean * sc;
        }
        __syncthreads();
    }
    const int c4 = tid & 31, rr = tid >> 5;
    const float4 sc = *(const float4*)&s_sc[c4 * 4];
    const float4 sh = *(const float4*)&s_sh[c4 * 4];
    #pragma unroll
    for (int it = 0; it < 8; ++it) {
        const int row = (blockIdx.x << 6) + (it << 3) + rr;
        const int* ip = idxmat + (size_t)row * KNN;
        float4 m = {0.f, 0.f, 0.f, 0.f};
        #pragma unroll
        for (int k = 0; k < KNN; ++k) {
            const int j = ip[k];
            const float4 v = *(const float4*)(Hin + (size_t)j * 128 + c4 * 4);
            m.x = fmaxf(m.x, fmaf(v.x, sc.x, sh.x));
            m.y = fmaxf(m.y, fmaf(v.y, sc.y, sh.y));
            m.z = fmaxf(m.z, fmaf(v.z, sc.z, sh.z));
            m.w = fmaxf(m.w, fmaf(v.w, sc.w, sh.w));
        }
        ushort4 hi, lo;
        hi.x = f2bf(m.x); lo.x = f2bf(m.x - bf2f(hi.x));
        hi.y = f2bf(m.y); lo.y = f2bf(m.y - bf2f(hi.y));
        hi.z = f2bf(m.z); lo.z = f2bf(m.z - bf2f(hi.z));
        hi.w = f2bf(m.w); lo.w = f2bf(m.w - bf2f(hi.w));
        *(ushort4*)(Zhi + (size_t)row * 128 + c4 * 4) = hi;
        *(ushort4*)(Zlo + (size_t)row * 128 + c4 * 4) = lo;
    }
}

// ---------- fused bnrelu + masked segment max, fp32 ----------
__global__ __launch_bounds__(256)
void segmax_bnrelu_f32(const float* __restrict__ Y, const float* __restrict__ scale,
                       const float* __restrict__ shift, const int* __restrict__ mask,
                       unsigned* __restrict__ pooled)
{
    __shared__ int mk[64];
    const int b = blockIdx.x, nc = blockIdx.y;
    const int n0 = nc * 64;
    if (threadIdx.x < 64) mk[threadIdx.x] = mask[b * NPTS + n0 + threadIdx.x];
    __syncthreads();
    const int c4 = threadIdx.x;
    const float4 sc = ((const float4*)scale)[c4], sh = ((const float4*)shift)[c4];
    float4 m = {0.f, 0.f, 0.f, 0.f};
    for (int n = 0; n < 64; ++n) {
        if (mk[n]) {
            const float4 v = ((const float4*)(Y + ((size_t)b * NPTS + n0 + n) * 1024))[c4];
            m.x = fmaxf(m.x, fmaf(v.x, sc.x, sh.x));
            m.y = fmaxf(m.y, fmaf(v.y, sc.y, sh.y));
            m.z = fmaxf(m.z, fmaf(v.z, sc.z, sh.z));
            m.w = fmaxf(m.w, fmaf(v.w, sc.w, sh.w));
        }
    }
    m.x = fmaxf(m.x, 0.f); m.y = fmaxf(m.y, 0.f); m.z = fmaxf(m.z, 0.f); m.w = fmaxf(m.w, 0.f);
    atomicMax(&pooled[b * 1024 + c4 * 4 + 0], __float_as_uint(m.x));
    atomicMax(&pooled[b * 1024 + c4 * 4 + 1], __float_as_uint(m.y));
    atomicMax(&pooled[b * 1024 + c4 * 4 + 2], __float_as_uint(m.z));
    atomicMax(&pooled[b * 1024 + c4 * 4 + 3], __float_as_uint(m.w));
}

// ---------- head: 8-row GEMM + BN(8) + ReLU, 4-way K split ----------
template<int KDIM>
__global__ __launch_bounds__(256)
void mlp8_kernel(const float* __restrict__ In, const float* __restrict__ W,
                 const float* __restrict__ bias, const float* __restrict__ g,
                 const float* __restrict__ be, float* __restrict__ Out)
{
    __shared__ float Ins[8 * KDIM];
    __shared__ float part[4][8][64];
    const int tid = threadIdx.x;
    for (int e = tid; e < 8 * KDIM; e += 256) Ins[e] = In[e];
    __syncthreads();
    const int kg = tid >> 6, cl = tid & 63;
    const int col = (blockIdx.x << 6) + cl;
    float a[8] = {};
    const int k1 = (kg + 1) * (KDIM / 4);
    for (int k = kg * (KDIM / 4); k < k1; ++k) {
        const float w = W[(size_t)k * 512 + col];
        #pragma unroll
        for (int r = 0; r < 8; ++r) a[r] = fmaf(Ins[r * KDIM + k], w, a[r]);
    }
    #pragma unroll
    for (int r = 0; r < 8; ++r) part[kg][r][cl] = a[r];
    __syncthreads();
    if (tid < 64) {
        const int c2 = (blockIdx.x << 6) + tid;
        const float bv = bias[c2];
        float y[8], s = 0.f, ss = 0.f;
        #pragma unroll
        for (int r = 0; r < 8; ++r) {
            y[r] = part[0][r][tid] + part[1][r][tid] + part[2][r][tid] + part[3][r][tid] + bv;
            s += y[r]; ss = fmaf(y[r], y[r], ss);
        }
        const float mean = s * 0.125f;
        const float var = fmaxf(ss * 0.125f - mean * mean, 0.f);
        const float sc = g[c2] * rsqrtf(var + 1e-5f);
        const float sh = be[c2] - mean * sc;
        #pragma unroll
        for (int r = 0; r < 8; ++r)
            Out[r * 512 + c2] = fmaxf(0.f, fmaf(y[r], sc, sh));
    }
}

// ---------- launcher ----------
extern "C" void kernel_launch(void* const* d_in, const int* in_sizes, int n_in,
                              void* d_out, int out_size, void* d_ws, size_t ws_size,
                              hipStream_t stream)
{
    const float* x    = (const float*)d_in[0];
    const int*   mask = (const int*)d_in[1];
    const float* w_m1a = (const float*)d_in[2];
    const float* b_m1a = (const float*)d_in[3];
    const float* g_m1a = (const float*)d_in[4];
    const float* be_m1a = (const float*)d_in[5];
    const float* w_m1b = (const float*)d_in[6];
    const float* b_m1b = (const float*)d_in[7];
    const float* g_m1b = (const float*)d_in[8];
    const float* be_m1b = (const float*)d_in[9];
    const float* w_m1c = (const float*)d_in[10];
    const float* b_m1c = (const float*)d_in[11];
    const float* g_m1c = (const float*)d_in[12];
    const float* be_m1c = (const float*)d_in[13];
    const float* w_gl1 = (const float*)d_in[14];
    const float* b_gl1 = (const float*)d_in[15];
    const float* g_gl1 = (const float*)d_in[16];
    const float* be_gl1 = (const float*)d_in[17];
    const float* w_gl2 = (const float*)d_in[18];
    const float* b_gl2 = (const float*)d_in[19];
    const float* g_gl2 = (const float*)d_in[20];
    const float* be_gl2 = (const float*)d_in[21];
    const float* w_m2a = (const float*)d_in[22];
    const float* b_m2a = (const float*)d_in[23];
    const float* g_m2a = (const float*)d_in[24];
    const float* be_m2a = (const float*)d_in[25];
    const float* w_m2b = (const float*)d_in[26];
    const float* b_m2b = (const float*)d_in[27];
    const float* g_m2b = (const float*)d_in[28];
    const float* be_m2b = (const float*)d_in[29];

    float* ws = (float*)d_ws;
    int*   idx  = (int*)ws;                              // +262144
    float* h0   = ws + 262144;                           // +196608
    float* bufA = ws + 458752;                           // +1048576
    float* bufB = ws + 1507328;                          // +1048576
    float* bufC = ws + 2555904;                          // +2097152
    unsigned short* wTh = (unsigned short*)(ws + 4653056);   // +65536
    unsigned short* wTl = (unsigned short*)(ws + 4718592);   // +65536
    float* bufE  = ws + 4784128;                         // +16777216
    float* pooled = ws + 21561344;                       // +8192
    float* y1     = ws + 21569536;                       // +4096
    float* ps0    = ws + 21573632;                       // +131072
    float* pss0   = ws + 21704704;                       // +131072
    float* ps1    = ws + 21835776;                       // +131072
    float* pss1   = ws + 21966848;                       // +131072
    float* scale  = ws + 22097920;                       // +1024
    float* shift  = ws + 22098944;                       // +1024 -> end 22099968 (88.4 MB)

    // Ahi/Alo alias dead bufA/bufB (free after gm64 / gl1 respectively)
    unsigned short* Ahi = (unsigned short*)bufA;
    unsigned short* Alo = (unsigned short*)bufB;

    hipMemsetAsync(pooled, 0, 8 * 1024 * sizeof(float), stream);
    cvt_wgl2_kernel<<<512, 256, 0, stream>>>(w_gl2, wTh, wTl);

    knn_cov_kernel<<<4096, 256, 0, stream>>>(x, mask, idx, h0);

    // m1a: 12 -> 64 (writes stats chunks to ps0)
    gemm_bias_kernel<false><<<dim3(256, 1), 256, 0, stream>>>(
        h0, w_m1a, b_m1a, nullptr, nullptr, nullptr, nullptr, bufA, ps0, pss0, 12, 64);
    // m1b: 64 -> 64 (folds bn_m1a from ps0; writes ps1)
    gemm_bias_kernel<true><<<dim3(256, 1), 256, 0, stream>>>(
        bufA, w_m1b, b_m1b, ps0, pss0, g_m1a, be_m1a, bufB, ps1, pss1, 64, 64);
    // m1c: 64 -> 64 (folds bn_m1b from ps1; writes ps0)
    gemm_bias_kernel<true><<<dim3(256, 1), 256, 0, stream>>>(
        bufB, w_m1c, b_m1c, ps1, pss1, g_m1b, be_m1b, bufA, ps0, pss0, 64, 64);

    // gather-max 64 (folds bn_m1c from ps0)
    gathermax_bn64<<<256, 256, 0, stream>>>(bufA, idx, ps0, pss0, g_m1c, be_m1c, bufB);

    // gl1: 64 -> 128 (writes ps1)
    gemm_bias_kernel<false><<<dim3(256, 2), 256, 0, stream>>>(
        bufB, w_gl1, b_gl1, nullptr, nullptr, nullptr, nullptr, bufC, ps1, pss1, 64, 128);

    // gather-max 128 (folds bn_gl1 from ps1) -> split-bf16 A
    gathermax_bn128_split<<<256, 256, 0, stream>>>(bufC, idx, ps1, pss1, g_gl1, be_gl1, Ahi, Alo);

    // gl2: 128 -> 1024, split-bf16 MFMA + fused stats chunks (ps0, 128 chunks)
    gemm_gl2_mfma<<<dim3(128, 8), 256, 0, stream>>>(Ahi, Alo, wTh, wTl, b_gl2, bufE, ps0, pss0);
    stats_final_kernel<<<4, 256, 0, stream>>>(ps0, pss0, g_gl2, be_gl2, scale, shift, 1024, 128);

    // fused bnrelu + masked segment-max
    segmax_bnrelu_f32<<<dim3(8, 32), 256, 0, stream>>>(bufE, scale, shift, mask, (unsigned*)pooled);

    // head
    mlp8_kernel<1024><<<8, 256, 0, stream>>>(pooled, w_m2a, b_m2a, g_m2a, be_m2a, y1);
    mlp8_kernel<512><<<8, 256, 0, stream>>>(y1, w_m2b, b_m2b, g_m2b, be_m2b, (float*)d_out);
}

// Round 7
// 421.679 us; speedup vs baseline: 1.6677x; 1.6677x over previous
//
#include <hip/hip_runtime.h>
#include <hip/hip_bf16.h>
#include <stdint.h>
#include <math.h>

#define NPTS 2048
#define BSZ 8
#define KNN 16
#define MROWS (BSZ * NPTS)   // 16384

typedef __attribute__((ext_vector_type(8))) short bf16x8;
typedef __attribute__((ext_vector_type(4))) float f32x4;

__device__ __forceinline__ unsigned short f2bf(float f) {
    __hip_bfloat16 h = __float2bfloat16(f);
    return *(unsigned short*)&h;
}
__device__ __forceinline__ float bf2f(unsigned short u) {
    return __uint_as_float(((unsigned)u) << 16);
}

// ---------- helpers ----------
__device__ __forceinline__ unsigned sortable32(float f) {
    unsigned u = __float_as_uint(f);
    return u ^ ((unsigned)((int)u >> 31) | 0x80000000u);
}

__device__ __forceinline__ void cas_asc(unsigned long long &a, unsigned long long &b) {
    unsigned long long lo = a < b ? a : b;
    unsigned long long hi = a < b ? b : a;
    a = lo; b = hi;
}

// ---------- KNN + covariance (R2/R5-proven: u64 insertion top-16, fully unrolled) ----------
__global__ __launch_bounds__(256)
void knn_cov_kernel(const float* __restrict__ x, const int* __restrict__ mask,
                    int* __restrict__ idx_out, float* __restrict__ h0)
{
    __shared__ float4 cand[NPTS];
    const int tid  = threadIdx.x;
    const int wave = tid >> 6;
    const int lane = tid & 63;
    const int b = blockIdx.x >> 9;
    const int q = ((blockIdx.x & 511) << 2) + wave;
    const float* xb = x + (size_t)b * 3 * NPTS;
    const int*   mb = mask + b * NPTS;

    for (int m = tid; m < NPTS; m += 256) {
        float px = xb[m], py = xb[NPTS + m], pz = xb[2 * NPTS + m];
        float sq = px * px + py * py + pz * pz;
        if (mb[m] != 1) sq = INFINITY;
        cand[m] = make_float4(px, py, pz, sq);
    }
    __syncthreads();

    const float4 qc = cand[q];
    const float qx = qc.x, qy = qc.y, qz = qc.z;
    const float sqn = qx * qx + qy * qy + qz * qz;

    // per-lane top-16 via branchless bubble insertion (ascending)
    unsigned long long list[16];
    #pragma unroll
    for (int i = 0; i < 16; ++i) list[i] = ~0ull;
    #pragma unroll
    for (int t = 0; t < 32; ++t) {
        const int m = t * 64 + lane;
        const float4 c = cand[m];
        const float dot = qx * c.x + qy * c.y + qz * c.z;
        const float d = fmaf(-2.f, dot, sqn + c.w);
        unsigned long long cur = ((unsigned long long)sortable32(d) << 32) | (unsigned)m;
        #pragma unroll
        for (int i = 0; i < 16; ++i) {
            const bool lt = cur < list[i];
            const unsigned long long lo = lt ? cur : list[i];
            const unsigned long long hi = lt ? list[i] : cur;
            list[i] = lo; cur = hi;
        }
    }

    // 6 cross-lane bitonic merge rounds: keep lowest 16 of (mine, partner)
    #pragma unroll
    for (int p = 1; p <= 32; p <<= 1) {
        unsigned long long c2[16];
        #pragma unroll
        for (int i = 0; i < 16; ++i) {
            const unsigned long long pr = __shfl_xor(list[15 - i], p, 64);
            c2[i] = list[i] < pr ? list[i] : pr;
        }
        #pragma unroll
        for (int j = 8; j > 0; j >>= 1) {
            #pragma unroll
            for (int i = 0; i < 16; ++i) {
                const int l = i ^ j;
                if (l > i) cas_asc(c2[i], c2[l]);
            }
        }
        #pragma unroll
        for (int i = 0; i < 16; ++i) list[i] = c2[i];
    }

    const int gq = b * NPTS + q;
    if (lane < KNN)
        idx_out[gq * KNN + lane] = b * NPTS + (int)(unsigned)list[lane];

    const int ml = (int)(unsigned)list[lane & 15];
    const float4 nb = cand[ml];
    float sx = nb.x, sy = nb.y, sz = nb.z;
    #pragma unroll
    for (int m = 1; m < 16; m <<= 1) {
        sx += __shfl_xor(sx, m, 64); sy += __shfl_xor(sy, m, 64); sz += __shfl_xor(sz, m, 64);
    }
    const float mx = sx * 0.0625f, my = sy * 0.0625f, mz = sz * 0.0625f;
    const float cx = nb.x - mx, cy = nb.y - my, cz = nb.z - mz;
    float xx = cx * cx, xy = cx * cy, xz = cx * cz;
    float yy = cy * cy, yz = cy * cz, zz = cz * cz;
    #pragma unroll
    for (int m = 1; m < 16; m <<= 1) {
        xx += __shfl_xor(xx, m, 64); xy += __shfl_xor(xy, m, 64); xz += __shfl_xor(xz, m, 64);
        yy += __shfl_xor(yy, m, 64); yz += __shfl_xor(yz, m, 64); zz += __shfl_xor(zz, m, 64);
    }
    if (lane == 0) {
        float* o = h0 + (size_t)gq * 12;
        o[0] = qx; o[1] = qy; o[2] = qz;
        o[3] = xx; o[4] = xy; o[5] = xz;
        o[6] = xy; o[7] = yy; o[8] = yz;
        o[9] = xz; o[10] = yz; o[11] = zz;
    }
}

// ---------- fp32 GEMM with fused stats output (+optional folded BN on X) ----------
template<bool BNX>
__global__ __launch_bounds__(256)
void gemm_bias_kernel(const float* __restrict__ X, const float* __restrict__ W,
                      const float* __restrict__ bias,
                      const float* __restrict__ bps, const float* __restrict__ bpss,
                      const float* __restrict__ bg, const float* __restrict__ bbe,
                      float* __restrict__ Y,
                      float* __restrict__ ops, float* __restrict__ opss,
                      int K, int C)
{
    __shared__ float Xs[16][65];
    __shared__ float Ws[16][65];
    __shared__ float s_sc[64], s_sh[64];
    __shared__ float rs[16][64], rss[16][64];
    const int tid = threadIdx.x;

    if (BNX) {
        const int c = tid & 63, part = tid >> 6;
        float s = 0.f, ss = 0.f;
        for (int i = part * 64; i < part * 64 + 64; ++i) {
            s += bps[(size_t)i * 64 + c];
            ss += bpss[(size_t)i * 64 + c];
        }
        rs[part][c] = s; rss[part][c] = ss;
        __syncthreads();
        if (tid < 64) {
            const float S  = rs[0][tid] + rs[1][tid] + rs[2][tid] + rs[3][tid];
            const float SS = rss[0][tid] + rss[1][tid] + rss[2][tid] + rss[3][tid];
            const float invM = 1.f / (float)MROWS;
            const float mean = S * invM;
            const float var = fmaxf(SS * invM - mean * mean, 0.f);
            const float sc = bg[tid] * rsqrtf(var + 1e-5f);
            s_sc[tid] = sc;
            s_sh[tid] = bbe[tid] - mean * sc;
        }
        __syncthreads();
    }

    const int bm = blockIdx.x << 6;
    const int bn = blockIdx.y << 6;
    const int ty = tid >> 4, tx = tid & 15;
    float acc[4][4] = {};
    for (int k0 = 0; k0 < K; k0 += 16) {
        #pragma unroll
        for (int e = tid; e < 1024; e += 256) {
            const int m = e >> 4, k = e & 15;
            float v = 0.f;
            if (k0 + k < K) {
                v = X[(size_t)(bm + m) * K + k0 + k];
                if (BNX) v = fmaxf(0.f, fmaf(v, s_sc[k0 + k], s_sh[k0 + k]));
            }
            Xs[k][m] = v;
        }
        #pragma unroll
        for (int e = tid; e < 1024; e += 256) {
            const int k = e >> 6, n = e & 63;
            Ws[k][n] = (k0 + k < K) ? W[(size_t)(k0 + k) * C + bn + n] : 0.f;
        }
        __syncthreads();
        #pragma unroll
        for (int k = 0; k < 16; ++k) {
            float a[4], bb[4];
            #pragma unroll
            for (int i = 0; i < 4; ++i) a[i] = Xs[k][ty * 4 + i];
            #pragma unroll
            for (int j = 0; j < 4; ++j) bb[j] = Ws[k][tx * 4 + j];
            #pragma unroll
            for (int i = 0; i < 4; ++i)
                #pragma unroll
                for (int j = 0; j < 4; ++j)
                    acc[i][j] = fmaf(a[i], bb[j], acc[i][j]);
        }
        __syncthreads();
    }

    float se[4] = {0.f, 0.f, 0.f, 0.f}, sse[4] = {0.f, 0.f, 0.f, 0.f};
    #pragma unroll
    for (int i = 0; i < 4; ++i) {
        const int r = bm + ty * 4 + i;
        #pragma unroll
        for (int j = 0; j < 4; ++j) {
            const int ccol = bn + tx * 4 + j;
            const float yv = acc[i][j] + bias[ccol];
            Y[(size_t)r * C + ccol] = yv;
            se[j] += yv; sse[j] = fmaf(yv, yv, sse[j]);
        }
    }
    #pragma unroll
    for (int j = 0; j < 4; ++j) { rs[ty][tx * 4 + j] = se[j]; rss[ty][tx * 4 + j] = sse[j]; }
    __syncthreads();
    if (tid < 64) {
        float S = 0.f, SS = 0.f;
        #pragma unroll
        for (int r2 = 0; r2 < 16; ++r2) { S += rs[r2][tid]; SS += rss[r2][tid]; }
        ops[(size_t)blockIdx.x * C + bn + tid] = S;
        opss[(size_t)blockIdx.x * C + bn + tid] = SS;
    }
}

// ---------- w_gl2 -> split bf16 transposed [n][k]: hi + lo(residual) ----------
__global__ void cvt_wgl2_kernel(const float* __restrict__ w,
                                unsigned short* __restrict__ wT_hi,
                                unsigned short* __restrict__ wT_lo)
{
    const int t = blockIdx.x * 256 + threadIdx.x;   // t = n*128 + k
    const int n = t >> 7, k = t & 127;
    const float v = w[(size_t)k * 1024 + n];
    const unsigned short hi = f2bf(v);
    wT_hi[t] = hi;
    wT_lo[t] = f2bf(v - bf2f(hi));
}

// ---------- gl2 MFMA GEMM (split-bf16, 3 passes) + fused psum chunks ----------
__global__ __launch_bounds__(256)
void gemm_gl2_mfma(const unsigned short* __restrict__ Ahi, const unsigned short* __restrict__ Alo,
                   const unsigned short* __restrict__ Whi, const unsigned short* __restrict__ Wlo,
                   const float* __restrict__ bias, float* __restrict__ Y,
                   float* __restrict__ ops, float* __restrict__ opss)
{
    __shared__ float ps[2][128], pss2[2][128];
    const int wave = threadIdx.x >> 6, lane = threadIdx.x & 63;
    const int wm = wave >> 1, wn = wave & 1;
    const int bm = blockIdx.x * 128 + wm * 64;
    const int bn = blockIdx.y * 128 + wn * 64;
    const int lrow = lane & 15;
    const int lk = (lane >> 4) * 8;
    f32x4 acc[4][4] = {};
    #pragma unroll
    for (int ks = 0; ks < 4; ++ks) {
        const int k0 = ks * 32 + lk;
        bf16x8 ah[4], al[4], bh[4], bl[4];
        #pragma unroll
        for (int mf = 0; mf < 4; ++mf) {
            const size_t off = (size_t)(bm + mf * 16 + lrow) * 128 + k0;
            ah[mf] = *(const bf16x8*)(Ahi + off);
            al[mf] = *(const bf16x8*)(Alo + off);
        }
        #pragma unroll
        for (int nf = 0; nf < 4; ++nf) {
            const size_t off = (size_t)(bn + nf * 16 + lrow) * 128 + k0;
            bh[nf] = *(const bf16x8*)(Whi + off);
            bl[nf] = *(const bf16x8*)(Wlo + off);
        }
        #pragma unroll
        for (int mf = 0; mf < 4; ++mf)
            #pragma unroll
            for (int nf = 0; nf < 4; ++nf) {
                acc[mf][nf] = __builtin_amdgcn_mfma_f32_16x16x32_bf16(ah[mf], bh[nf], acc[mf][nf], 0, 0, 0);
                acc[mf][nf] = __builtin_amdgcn_mfma_f32_16x16x32_bf16(ah[mf], bl[nf], acc[mf][nf], 0, 0, 0);
                acc[mf][nf] = __builtin_amdgcn_mfma_f32_16x16x32_bf16(al[mf], bh[nf], acc[mf][nf], 0, 0, 0);
            }
    }
    const int r0 = (lane >> 4) * 4, cc = lane & 15;
    float s[4] = {0.f, 0.f, 0.f, 0.f}, sq2[4] = {0.f, 0.f, 0.f, 0.f};
    #pragma unroll
    for (int mf = 0; mf < 4; ++mf) {
        const int row = bm + mf * 16 + r0;
        #pragma unroll
        for (int nf = 0; nf < 4; ++nf) {
            const int col = bn + nf * 16 + cc;
            const float bv = bias[col];
            #pragma unroll
            for (int r = 0; r < 4; ++r) {
                const float yv = acc[mf][nf][r] + bv;
                Y[(size_t)(row + r) * 1024 + col] = yv;
                s[nf] += yv; sq2[nf] = fmaf(yv, yv, sq2[nf]);
            }
        }
    }
    #pragma unroll
    for (int nf = 0; nf < 4; ++nf) {
        #pragma unroll
        for (int off = 16; off < 64; off <<= 1) {
            s[nf]   += __shfl_xor(s[nf], off, 64);
            sq2[nf] += __shfl_xor(sq2[nf], off, 64);
        }
    }
    if (lane < 16) {
        #pragma unroll
        for (int nf = 0; nf < 4; ++nf) {
            ps[wm][wn * 64 + nf * 16 + lane] = s[nf];
            pss2[wm][wn * 64 + nf * 16 + lane] = sq2[nf];
        }
    }
    __syncthreads();
    if (threadIdx.x < 128) {
        const size_t o = (size_t)blockIdx.x * 1024 + blockIdx.y * 128 + threadIdx.x;
        ops[o]  = ps[0][threadIdx.x] + ps[1][threadIdx.x];
        opss[o] = pss2[0][threadIdx.x] + pss2[1][threadIdx.x];
    }
}

// ---------- stats final (gl2 only) ----------
__global__ void stats_final_kernel(const float* __restrict__ psum, const float* __restrict__ psumsq,
                                   const float* __restrict__ g, const float* __restrict__ be,
                                   float* __restrict__ scale, float* __restrict__ shift,
                                   int C, int nchunks)
{
    const int c = blockIdx.x * 256 + threadIdx.x;
    if (c >= C) return;
    float s = 0.f, ss = 0.f;
    for (int i = 0; i < nchunks; ++i) { s += psum[(size_t)i * C + c]; ss += psumsq[(size_t)i * C + c]; }
    const float invM = 1.f / (float)MROWS;
    const float mean = s * invM;
    const float var = fmaxf(ss * invM - mean * mean, 0.f);
    const float sc = g[c] * rsqrtf(var + 1e-5f);
    scale[c] = sc;
    shift[c] = be[c] - mean * sc;
}

// ---------- gather-max + folded BN-final, 64 ch ----------
__global__ __launch_bounds__(256)
void gathermax_bn64(const float* __restrict__ Hin, const int* __restrict__ idxmat,
                    const float* __restrict__ bps, const float* __restrict__ bpss,
                    const float* __restrict__ bg, const float* __restrict__ bbe,
                    float* __restrict__ Z)
{
    __shared__ float s_sc[64], s_sh[64];
    __shared__ float red[4][64], red2[4][64];
    const int tid = threadIdx.x;
    {
        const int c = tid & 63, part = tid >> 6;
        float s = 0.f, ss = 0.f;
        for (int i = part * 64; i < part * 64 + 64; ++i) {
            s += bps[(size_t)i * 64 + c]; ss += bpss[(size_t)i * 64 + c];
        }
        red[part][c] = s; red2[part][c] = ss;
        __syncthreads();
        if (tid < 64) {
            const float S  = red[0][tid] + red[1][tid] + red[2][tid] + red[3][tid];
            const float SS = red2[0][tid] + red2[1][tid] + red2[2][tid] + red2[3][tid];
            const float invM = 1.f / (float)MROWS;
            const float mean = S * invM;
            const float var = fmaxf(SS * invM - mean * mean, 0.f);
            const float sc = bg[tid] * rsqrtf(var + 1e-5f);
            s_sc[tid] = sc; s_sh[tid] = bbe[tid] - mean * sc;
        }
        __syncthreads();
    }
    const int c4 = tid & 15, rr = tid >> 4;
    const float4 sc = *(const float4*)&s_sc[c4 * 4];
    const float4 sh = *(const float4*)&s_sh[c4 * 4];
    #pragma unroll
    for (int it = 0; it < 4; ++it) {
        const int row = (blockIdx.x << 6) + (it << 4) + rr;
        const int* ip = idxmat + (size_t)row * KNN;
        float4 m = {0.f, 0.f, 0.f, 0.f};
        #pragma unroll
        for (int k = 0; k < KNN; ++k) {
            const int j = ip[k];
            const float4 v = *(const float4*)(Hin + (size_t)j * 64 + c4 * 4);
            m.x = fmaxf(m.x, fmaf(v.x, sc.x, sh.x));
            m.y = fmaxf(m.y, fmaf(v.y, sc.y, sh.y));
            m.z = fmaxf(m.z, fmaf(v.z, sc.z, sh.z));
            m.w = fmaxf(m.w, fmaf(v.w, sc.w, sh.w));
        }
        ((float4*)(Z + (size_t)row * 64))[c4] = m;
    }
}

// ---------- gather-max + folded BN-final, 128 ch, split-bf16 out ----------
__global__ __launch_bounds__(256)
void gathermax_bn128_split(const float* __restrict__ Hin, const int* __restrict__ idxmat,
                           const float* __restrict__ bps, const float* __restrict__ bpss,
                           const float* __restrict__ bg, const float* __restrict__ bbe,
                           unsigned short* __restrict__ Zhi, unsigned short* __restrict__ Zlo)
{
    __shared__ float s_sc[128], s_sh[128];
    __shared__ float red[2][128], red2[2][128];
    const int tid = threadIdx.x;
    {
        const int c = tid & 127, part = tid >> 7;
        float s = 0.f, ss = 0.f;
        for (int i = part * 128; i < part * 128 + 128; ++i) {
            s += bps[(size_t)i * 128 + c]; ss += bpss[(size_t)i * 128 + c];
        }
        red[part][c] = s; red2[part][c] = ss;
        __syncthreads();
        if (tid < 128) {
            const float S  = red[0][tid] + red[1][tid];
            const float SS = red2[0][tid] + red2[1][tid];
            const float invM = 1.f / (float)MROWS;
            const float mean = S * invM;
            const float var = fmaxf(SS * invM - mean * mean, 0.f);
            const float sc = bg[tid] * rsqrtf(var + 1e-5f);
            s_sc[tid] = sc; s_sh[tid] = bbe[tid] - mean * sc;
        }
        __syncthreads();
    }
    const int c4 = tid & 31, rr = tid >> 5;
    const float4 sc = *(const float4*)&s_sc[c4 * 4];
    const float4 sh = *(const float4*)&s_sh[c4 * 4];
    #pragma unroll
    for (int it = 0; it < 8; ++it) {
        const int row = (blockIdx.x << 6) + (it << 3) + rr;
        const int* ip = idxmat + (size_t)row * KNN;
        float4 m = {0.f, 0.f, 0.f, 0.f};
        #pragma unroll
        for (int k = 0; k < KNN; ++k) {
            const int j = ip[k];
            const float4 v = *(const float4*)(Hin + (size_t)j * 128 + c4 * 4);
            m.x = fmaxf(m.x, fmaf(v.x, sc.x, sh.x));
            m.y = fmaxf(m.y, fmaf(v.y, sc.y, sh.y));
            m.z = fmaxf(m.z, fmaf(v.z, sc.z, sh.z));
            m.w = fmaxf(m.w, fmaf(v.w, sc.w, sh.w));
        }
        ushort4 hi, lo;
        hi.x = f2bf(m.x); lo.x = f2bf(m.x - bf2f(hi.x));
        hi.y = f2bf(m.y); lo.y = f2bf(m.y - bf2f(hi.y));
        hi.z = f2bf(m.z); lo.z = f2bf(m.z - bf2f(hi.z));
        hi.w = f2bf(m.w); lo.w = f2bf(m.w - bf2f(hi.w));
        *(ushort4*)(Zhi + (size_t)row * 128 + c4 * 4) = hi;
        *(ushort4*)(Zlo + (size_t)row * 128 + c4 * 4) = lo;
    }
}

// ---------- fused bnrelu + masked segment max, fp32 ----------
__global__ __launch_bounds__(256)
void segmax_bnrelu_f32(const float* __restrict__ Y, const float* __restrict__ scale,
                       const float* __restrict__ shift, const int* __restrict__ mask,
                       unsigned* __restrict__ pooled)
{
    __shared__ int mk[64];
    const int b = blockIdx.x, nc = blockIdx.y;
    const int n0 = nc * 64;
    if (threadIdx.x < 64) mk[threadIdx.x] = mask[b * NPTS + n0 + threadIdx.x];
    __syncthreads();
    const int c4 = threadIdx.x;
    const float4 sc = ((const float4*)scale)[c4], sh = ((const float4*)shift)[c4];
    float4 m = {0.f, 0.f, 0.f, 0.f};
    for (int n = 0; n < 64; ++n) {
        if (mk[n]) {
            const float4 v = ((const float4*)(Y + ((size_t)b * NPTS + n0 + n) * 1024))[c4];
            m.x = fmaxf(m.x, fmaf(v.x, sc.x, sh.x));
            m.y = fmaxf(m.y, fmaf(v.y, sc.y, sh.y));
            m.z = fmaxf(m.z, fmaf(v.z, sc.z, sh.z));
            m.w = fmaxf(m.w, fmaf(v.w, sc.w, sh.w));
        }
    }
    m.x = fmaxf(m.x, 0.f); m.y = fmaxf(m.y, 0.f); m.z = fmaxf(m.z, 0.f); m.w = fmaxf(m.w, 0.f);
    atomicMax(&pooled[b * 1024 + c4 * 4 + 0], __float_as_uint(m.x));
    atomicMax(&pooled[b * 1024 + c4 * 4 + 1], __float_as_uint(m.y));
    atomicMax(&pooled[b * 1024 + c4 * 4 + 2], __float_as_uint(m.z));
    atomicMax(&pooled[b * 1024 + c4 * 4 + 3], __float_as_uint(m.w));
}

// ---------- head: 8-row GEMM + BN(8) + ReLU; 64 blocks x 8 cols, 32-way K-split ----------
template<int KDIM>
__global__ __launch_bounds__(256)
void mlp8_kernel(const float* __restrict__ In, const float* __restrict__ W,
                 const float* __restrict__ bias, const float* __restrict__ g,
                 const float* __restrict__ be, float* __restrict__ Out)
{
    __shared__ float Ins[8 * KDIM];
    __shared__ float part[32][8][8];
    __shared__ float ys[8][8];
    const int tid = threadIdx.x;
    for (int e = tid; e < 8 * KDIM; e += 256) Ins[e] = In[e];
    __syncthreads();
    const int c = tid & 7, kp = tid >> 3;      // 8 cols x 32 k-parts
    const int col = (blockIdx.x << 3) + c;
    constexpr int KS = KDIM / 32;
    float a[8] = {};
    for (int k = kp * KS; k < (kp + 1) * KS; ++k) {
        const float w = W[(size_t)k * 512 + col];
        #pragma unroll
        for (int r = 0; r < 8; ++r) a[r] = fmaf(Ins[r * KDIM + k], w, a[r]);
    }
    #pragma unroll
    for (int r = 0; r < 8; ++r) part[kp][r][c] = a[r];
    __syncthreads();
    if (tid < 64) {
        const int r = tid >> 3, cc = tid & 7;
        float s = 0.f;
        #pragma unroll
        for (int p = 0; p < 32; ++p) s += part[p][r][cc];
        ys[r][cc] = s + bias[(blockIdx.x << 3) + cc];
    }
    __syncthreads();
    if (tid < 8) {
        const int c2 = (blockIdx.x << 3) + tid;
        float s = 0.f, ss = 0.f;
        #pragma unroll
        for (int r = 0; r < 8; ++r) { const float v = ys[r][tid]; s += v; ss = fmaf(v, v, ss); }
        const float mean = s * 0.125f;
        const float var = fmaxf(ss * 0.125f - mean * mean, 0.f);
        const float sc = g[c2] * rsqrtf(var + 1e-5f);
        const float sh = be[c2] - mean * sc;
        #pragma unroll
        for (int r = 0; r < 8; ++r)
            Out[r * 512 + c2] = fmaxf(0.f, fmaf(ys[r][tid], sc, sh));
    }
}

// ---------- launcher ----------
extern "C" void kernel_launch(void* const* d_in, const int* in_sizes, int n_in,
                              void* d_out, int out_size, void* d_ws, size_t ws_size,
                              hipStream_t stream)
{
    const float* x    = (const float*)d_in[0];
    const int*   mask = (const int*)d_in[1];
    const float* w_m1a = (const float*)d_in[2];
    const float* b_m1a = (const float*)d_in[3];
    const float* g_m1a = (const float*)d_in[4];
    const float* be_m1a = (const float*)d_in[5];
    const float* w_m1b = (const float*)d_in[6];
    const float* b_m1b = (const float*)d_in[7];
    const float* g_m1b = (const float*)d_in[8];
    const float* be_m1b = (const float*)d_in[9];
    const float* w_m1c = (const float*)d_in[10];
    const float* b_m1c = (const float*)d_in[11];
    const float* g_m1c = (const float*)d_in[12];
    const float* be_m1c = (const float*)d_in[13];
    const float* w_gl1 = (const float*)d_in[14];
    const float* b_gl1 = (const float*)d_in[15];
    const float* g_gl1 = (const float*)d_in[16];
    const float* be_gl1 = (const float*)d_in[17];
    const float* w_gl2 = (const float*)d_in[18];
    const float* b_gl2 = (const float*)d_in[19];
    const float* g_gl2 = (const float*)d_in[20];
    const float* be_gl2 = (const float*)d_in[21];
    const float* w_m2a = (const float*)d_in[22];
    const float* b_m2a = (const float*)d_in[23];
    const float* g_m2a = (const float*)d_in[24];
    const float* be_m2a = (const float*)d_in[25];
    const float* w_m2b = (const float*)d_in[26];
    const float* b_m2b = (const float*)d_in[27];
    const float* g_m2b = (const float*)d_in[28];
    const float* be_m2b = (const float*)d_in[29];

    float* ws = (float*)d_ws;
    int*   idx  = (int*)ws;                              // +262144
    float* h0   = ws + 262144;                           // +196608
    float* bufA = ws + 458752;                           // +1048576
    float* bufB = ws + 1507328;                          // +1048576
    float* bufC = ws + 2555904;                          // +2097152
    unsigned short* wTh = (unsigned short*)(ws + 4653056);   // +65536
    unsigned short* wTl = (unsigned short*)(ws + 4718592);   // +65536
    float* bufE  = ws + 4784128;                         // +16777216
    float* pooled = ws + 21561344;                       // +8192
    float* y1     = ws + 21569536;                       // +4096
    float* ps0    = ws + 21573632;                       // +131072
    float* pss0   = ws + 21704704;                       // +131072
    float* ps1    = ws + 21835776;                       // +131072
    float* pss1   = ws + 21966848;                       // +131072
    float* scale  = ws + 22097920;                       // +1024
    float* shift  = ws + 22098944;                       // +1024

    unsigned short* Ahi = (unsigned short*)bufA;
    unsigned short* Alo = (unsigned short*)bufB;

    hipMemsetAsync(pooled, 0, 8 * 1024 * sizeof(float), stream);
    cvt_wgl2_kernel<<<512, 256, 0, stream>>>(w_gl2, wTh, wTl);

    knn_cov_kernel<<<4096, 256, 0, stream>>>(x, mask, idx, h0);

    // m1a: 12 -> 64 (writes stats chunks to ps0)
    gemm_bias_kernel<false><<<dim3(256, 1), 256, 0, stream>>>(
        h0, w_m1a, b_m1a, nullptr, nullptr, nullptr, nullptr, bufA, ps0, pss0, 12, 64);
    // m1b: 64 -> 64 (folds bn_m1a from ps0; writes ps1)
    gemm_bias_kernel<true><<<dim3(256, 1), 256, 0, stream>>>(
        bufA, w_m1b, b_m1b, ps0, pss0, g_m1a, be_m1a, bufB, ps1, pss1, 64, 64);
    // m1c: 64 -> 64 (folds bn_m1b from ps1; writes ps0)
    gemm_bias_kernel<true><<<dim3(256, 1), 256, 0, stream>>>(
        bufB, w_m1c, b_m1c, ps1, pss1, g_m1b, be_m1b, bufA, ps0, pss0, 64, 64);

    // gather-max 64 (folds bn_m1c from ps0)
    gathermax_bn64<<<256, 256, 0, stream>>>(bufA, idx, ps0, pss0, g_m1c, be_m1c, bufB);

    // gl1: 64 -> 128 (writes ps1)
    gemm_bias_kernel<false><<<dim3(256, 2), 256, 0, stream>>>(
        bufB, w_gl1, b_gl1, nullptr, nullptr, nullptr, nullptr, bufC, ps1, pss1, 64, 128);

    // gather-max 128 (folds bn_gl1 from ps1) -> split-bf16 A
    gathermax_bn128_split<<<256, 256, 0, stream>>>(bufC, idx, ps1, pss1, g_gl1, be_gl1, Ahi, Alo);

    // gl2: 128 -> 1024, split-bf16 MFMA + fused stats chunks
    gemm_gl2_mfma<<<dim3(128, 8), 256, 0, stream>>>(Ahi, Alo, wTh, wTl, b_gl2, bufE, ps0, pss0);
    stats_final_kernel<<<4, 256, 0, stream>>>(ps0, pss0, g_gl2, be_gl2, scale, shift, 1024, 128);

    // fused bnrelu + masked segment-max
    segmax_bnrelu_f32<<<dim3(8, 32), 256, 0, stream>>>(bufE, scale, shift, mask, (unsigned*)pooled);

    // head
    mlp8_kernel<1024><<<64, 256, 0, stream>>>(pooled, w_m2a, b_m2a, g_m2a, be_m2a, y1);
    mlp8_kernel<512><<<64, 256, 0, stream>>>(y1, w_m2b, b_m2b, g_m2b, be_m2b, (float*)d_out);
}

// Round 8
// 388.324 us; speedup vs baseline: 1.8109x; 1.0859x over previous
//
#include <hip/hip_runtime.h>
#include <hip/hip_bf16.h>
#include <stdint.h>
#include <math.h>

#define NPTS 2048
#define BSZ 8
#define KNN 16
#define MROWS (BSZ * NPTS)   // 16384

typedef __attribute__((ext_vector_type(8))) short bf16x8;
typedef __attribute__((ext_vector_type(4))) float f32x4;

__device__ __forceinline__ unsigned short f2bf(float f) {
    __hip_bfloat16 h = __float2bfloat16(f);
    return *(unsigned short*)&h;
}
__device__ __forceinline__ float bf2f(unsigned short u) {
    return __uint_as_float(((unsigned)u) << 16);
}

// ---------- helpers ----------
__device__ __forceinline__ unsigned sortable32(float f) {
    unsigned u = __float_as_uint(f);
    return u ^ ((unsigned)((int)u >> 31) | 0x80000000u);
}

__device__ __forceinline__ void cas_asc(unsigned long long &a, unsigned long long &b) {
    unsigned long long lo = a < b ? a : b;
    unsigned long long hi = a < b ? b : a;
    a = lo; b = hi;
}

__device__ __forceinline__ void sort16u(unsigned long long k[16]) {
    #pragma unroll
    for (int kk = 2; kk <= 16; kk <<= 1) {
        #pragma unroll
        for (int j = kk >> 1; j > 0; j >>= 1) {
            #pragma unroll
            for (int i = 0; i < 16; ++i) {
                const int l = i ^ j;
                if (l > i) {
                    if ((i & kk) == 0) cas_asc(k[i], k[l]);
                    else               cas_asc(k[l], k[i]);
                }
            }
        }
    }
}

__device__ __forceinline__ void clean16u(unsigned long long k[16]) {
    #pragma unroll
    for (int j = 8; j > 0; j >>= 1) {
        #pragma unroll
        for (int i = 0; i < 16; ++i) {
            const int l = i ^ j;
            if (l > i) cas_asc(k[i], k[l]);
        }
    }
}

// ---------- KNN + covariance (+ folded w_gl2 conversion blocks) ----------
// blocks [0,4096): 4 queries per block (1/wave). blocks [4096,4608): cvt w_gl2.
// Phase 1 per lane: sort16(chunk0), sort16(chunk1), bitonic merge keep-16.
// Phase 2: 6 cross-lane bitonic merge rounds (proven).
__global__ __launch_bounds__(256)
void knn_cov_kernel(const float* __restrict__ x, const int* __restrict__ mask,
                    int* __restrict__ idx_out, float* __restrict__ h0,
                    const float* __restrict__ w_gl2,
                    unsigned short* __restrict__ wTh, unsigned short* __restrict__ wTl)
{
    const int tid = threadIdx.x;
    if (blockIdx.x >= 4096) {
        const int t = (blockIdx.x - 4096) * 256 + tid;   // t = n*128 + k
        const int n = t >> 7, k = t & 127;
        const float v = w_gl2[(size_t)k * 1024 + n];
        const unsigned short hi = f2bf(v);
        wTh[t] = hi;
        wTl[t] = f2bf(v - bf2f(hi));
        return;
    }

    __shared__ float4 cand[NPTS];
    const int wave = tid >> 6;
    const int lane = tid & 63;
    const int b = blockIdx.x >> 9;
    const int q = ((blockIdx.x & 511) << 2) + wave;
    const float* xb = x + (size_t)b * 3 * NPTS;
    const int*   mb = mask + b * NPTS;

    for (int m = tid; m < NPTS; m += 256) {
        float px = xb[m], py = xb[NPTS + m], pz = xb[2 * NPTS + m];
        float sq = px * px + py * py + pz * pz;
        if (mb[m] != 1) sq = INFINITY;
        cand[m] = make_float4(px, py, pz, sq);
    }
    __syncthreads();

    const float4 qc = cand[q];
    const float qx = qc.x, qy = qc.y, qz = qc.z;
    const float sqn = qx * qx + qy * qy + qz * qz;

    // chunk 0: candidates 0..1023 (16 per lane), sorted
    unsigned long long ld[16];
    #pragma unroll
    for (int t = 0; t < 16; ++t) {
        const int m = t * 64 + lane;
        const float4 c = cand[m];
        const float d = fmaf(-2.f, qx * c.x + qy * c.y + qz * c.z, sqn + c.w);
        ld[t] = ((unsigned long long)sortable32(d) << 32) | (unsigned)m;
    }
    sort16u(ld);

    // chunk 1: candidates 1024..2047, sorted
    unsigned long long cb[16];
    #pragma unroll
    for (int t = 0; t < 16; ++t) {
        const int m = (16 + t) * 64 + lane;
        const float4 c = cand[m];
        const float d = fmaf(-2.f, qx * c.x + qy * c.y + qz * c.z, sqn + c.w);
        cb[t] = ((unsigned long long)sortable32(d) << 32) | (unsigned)m;
    }
    sort16u(cb);

    // merge keep-lowest-16
    {
        unsigned long long mg[16];
        #pragma unroll
        for (int i = 0; i < 16; ++i) {
            const unsigned long long a = ld[i], b2 = cb[15 - i];
            mg[i] = a < b2 ? a : b2;
        }
        clean16u(mg);
        #pragma unroll
        for (int i = 0; i < 16; ++i) ld[i] = mg[i];
    }

    // phase 2: 6 cross-lane bitonic merge rounds (proven)
    #pragma unroll
    for (int p = 1; p <= 32; p <<= 1) {
        unsigned long long c2[16];
        #pragma unroll
        for (int i = 0; i < 16; ++i) {
            const unsigned long long pr = __shfl_xor(ld[15 - i], p, 64);
            c2[i] = ld[i] < pr ? ld[i] : pr;
        }
        clean16u(c2);
        #pragma unroll
        for (int i = 0; i < 16; ++i) ld[i] = c2[i];
    }

    const int gq = b * NPTS + q;
    if (lane < KNN)
        idx_out[gq * KNN + lane] = b * NPTS + (int)(unsigned)ld[lane];

    const int ml = (int)(unsigned)ld[lane & 15];
    const float4 nb = cand[ml];
    float sx = nb.x, sy = nb.y, sz = nb.z;
    #pragma unroll
    for (int m = 1; m < 16; m <<= 1) {
        sx += __shfl_xor(sx, m, 64); sy += __shfl_xor(sy, m, 64); sz += __shfl_xor(sz, m, 64);
    }
    const float mx = sx * 0.0625f, my = sy * 0.0625f, mz = sz * 0.0625f;
    const float cx = nb.x - mx, cy = nb.y - my, cz = nb.z - mz;
    float xx = cx * cx, xy = cx * cy, xz = cx * cz;
    float yy = cy * cy, yz = cy * cz, zz = cz * cz;
    #pragma unroll
    for (int m = 1; m < 16; m <<= 1) {
        xx += __shfl_xor(xx, m, 64); xy += __shfl_xor(xy, m, 64); xz += __shfl_xor(xz, m, 64);
        yy += __shfl_xor(yy, m, 64); yz += __shfl_xor(yz, m, 64); zz += __shfl_xor(zz, m, 64);
    }
    if (lane == 0) {
        float* o = h0 + (size_t)gq * 12;
        o[0] = qx; o[1] = qy; o[2] = qz;
        o[3] = xx; o[4] = xy; o[5] = xz;
        o[6] = xy; o[7] = yy; o[8] = yz;
        o[9] = xz; o[10] = yz; o[11] = zz;
    }
}

// ---------- fp32 GEMM with fused stats output (+optional folded BN on X) ----------
template<bool BNX>
__global__ __launch_bounds__(256)
void gemm_bias_kernel(const float* __restrict__ X, const float* __restrict__ W,
                      const float* __restrict__ bias,
                      const float* __restrict__ bps, const float* __restrict__ bpss,
                      const float* __restrict__ bg, const float* __restrict__ bbe,
                      float* __restrict__ Y,
                      float* __restrict__ ops, float* __restrict__ opss,
                      int K, int C)
{
    __shared__ float Xs[16][65];
    __shared__ float Ws[16][65];
    __shared__ float s_sc[64], s_sh[64];
    __shared__ float rs[16][64], rss[16][64];
    const int tid = threadIdx.x;

    if (BNX) {
        const int c = tid & 63, part = tid >> 6;
        float s = 0.f, ss = 0.f;
        for (int i = part * 64; i < part * 64 + 64; ++i) {
            s += bps[(size_t)i * 64 + c];
            ss += bpss[(size_t)i * 64 + c];
        }
        rs[part][c] = s; rss[part][c] = ss;
        __syncthreads();
        if (tid < 64) {
            const float S  = rs[0][tid] + rs[1][tid] + rs[2][tid] + rs[3][tid];
            const float SS = rss[0][tid] + rss[1][tid] + rss[2][tid] + rss[3][tid];
            const float invM = 1.f / (float)MROWS;
            const float mean = S * invM;
            const float var = fmaxf(SS * invM - mean * mean, 0.f);
            const float sc = bg[tid] * rsqrtf(var + 1e-5f);
            s_sc[tid] = sc;
            s_sh[tid] = bbe[tid] - mean * sc;
        }
        __syncthreads();
    }

    const int bm = blockIdx.x << 6;
    const int bn = blockIdx.y << 6;
    const int ty = tid >> 4, tx = tid & 15;
    float acc[4][4] = {};
    for (int k0 = 0; k0 < K; k0 += 16) {
        #pragma unroll
        for (int e = tid; e < 1024; e += 256) {
            const int m = e >> 4, k = e & 15;
            float v = 0.f;
            if (k0 + k < K) {
                v = X[(size_t)(bm + m) * K + k0 + k];
                if (BNX) v = fmaxf(0.f, fmaf(v, s_sc[k0 + k], s_sh[k0 + k]));
            }
            Xs[k][m] = v;
        }
        #pragma unroll
        for (int e = tid; e < 1024; e += 256) {
            const int k = e >> 6, n = e & 63;
            Ws[k][n] = (k0 + k < K) ? W[(size_t)(k0 + k) * C + bn + n] : 0.f;
        }
        __syncthreads();
        #pragma unroll
        for (int k = 0; k < 16; ++k) {
            float a[4], bb[4];
            #pragma unroll
            for (int i = 0; i < 4; ++i) a[i] = Xs[k][ty * 4 + i];
            #pragma unroll
            for (int j = 0; j < 4; ++j) bb[j] = Ws[k][tx * 4 + j];
            #pragma unroll
            for (int i = 0; i < 4; ++i)
                #pragma unroll
                for (int j = 0; j < 4; ++j)
                    acc[i][j] = fmaf(a[i], bb[j], acc[i][j]);
        }
        __syncthreads();
    }

    float se[4] = {0.f, 0.f, 0.f, 0.f}, sse[4] = {0.f, 0.f, 0.f, 0.f};
    #pragma unroll
    for (int i = 0; i < 4; ++i) {
        const int r = bm + ty * 4 + i;
        #pragma unroll
        for (int j = 0; j < 4; ++j) {
            const int ccol = bn + tx * 4 + j;
            const float yv = acc[i][j] + bias[ccol];
            Y[(size_t)r * C + ccol] = yv;
            se[j] += yv; sse[j] = fmaf(yv, yv, sse[j]);
        }
    }
    #pragma unroll
    for (int j = 0; j < 4; ++j) { rs[ty][tx * 4 + j] = se[j]; rss[ty][tx * 4 + j] = sse[j]; }
    __syncthreads();
    if (tid < 64) {
        float S = 0.f, SS = 0.f;
        #pragma unroll
        for (int r2 = 0; r2 < 16; ++r2) { S += rs[r2][tid]; SS += rss[r2][tid]; }
        ops[(size_t)blockIdx.x * C + bn + tid] = S;
        opss[(size_t)blockIdx.x * C + bn + tid] = SS;
    }
}

// ---------- gl2 MFMA GEMM (split-bf16, 3 passes) + fused psum chunks ----------
__global__ __launch_bounds__(256)
void gemm_gl2_mfma(const unsigned short* __restrict__ Ahi, const unsigned short* __restrict__ Alo,
                   const unsigned short* __restrict__ Whi, const unsigned short* __restrict__ Wlo,
                   const float* __restrict__ bias, float* __restrict__ Y,
                   float* __restrict__ ops, float* __restrict__ opss)
{
    __shared__ float ps[2][128], pss2[2][128];
    const int wave = threadIdx.x >> 6, lane = threadIdx.x & 63;
    const int wm = wave >> 1, wn = wave & 1;
    const int bm = blockIdx.x * 128 + wm * 64;
    const int bn = blockIdx.y * 128 + wn * 64;
    const int lrow = lane & 15;
    const int lk = (lane >> 4) * 8;
    f32x4 acc[4][4] = {};
    #pragma unroll
    for (int ks = 0; ks < 4; ++ks) {
        const int k0 = ks * 32 + lk;
        bf16x8 ah[4], al[4], bh[4], bl[4];
        #pragma unroll
        for (int mf = 0; mf < 4; ++mf) {
            const size_t off = (size_t)(bm + mf * 16 + lrow) * 128 + k0;
            ah[mf] = *(const bf16x8*)(Ahi + off);
            al[mf] = *(const bf16x8*)(Alo + off);
        }
        #pragma unroll
        for (int nf = 0; nf < 4; ++nf) {
            const size_t off = (size_t)(bn + nf * 16 + lrow) * 128 + k0;
            bh[nf] = *(const bf16x8*)(Whi + off);
            bl[nf] = *(const bf16x8*)(Wlo + off);
        }
        #pragma unroll
        for (int mf = 0; mf < 4; ++mf)
            #pragma unroll
            for (int nf = 0; nf < 4; ++nf) {
                acc[mf][nf] = __builtin_amdgcn_mfma_f32_16x16x32_bf16(ah[mf], bh[nf], acc[mf][nf], 0, 0, 0);
                acc[mf][nf] = __builtin_amdgcn_mfma_f32_16x16x32_bf16(ah[mf], bl[nf], acc[mf][nf], 0, 0, 0);
                acc[mf][nf] = __builtin_amdgcn_mfma_f32_16x16x32_bf16(al[mf], bh[nf], acc[mf][nf], 0, 0, 0);
            }
    }
    const int r0 = (lane >> 4) * 4, cc = lane & 15;
    float s[4] = {0.f, 0.f, 0.f, 0.f}, sq2[4] = {0.f, 0.f, 0.f, 0.f};
    #pragma unroll
    for (int mf = 0; mf < 4; ++mf) {
        const int row = bm + mf * 16 + r0;
        #pragma unroll
        for (int nf = 0; nf < 4; ++nf) {
            const int col = bn + nf * 16 + cc;
            const float bv = bias[col];
            #pragma unroll
            for (int r = 0; r < 4; ++r) {
                const float yv = acc[mf][nf][r] + bv;
                Y[(size_t)(row + r) * 1024 + col] = yv;
                s[nf] += yv; sq2[nf] = fmaf(yv, yv, sq2[nf]);
            }
        }
    }
    #pragma unroll
    for (int nf = 0; nf < 4; ++nf) {
        #pragma unroll
        for (int off = 16; off < 64; off <<= 1) {
            s[nf]   += __shfl_xor(s[nf], off, 64);
            sq2[nf] += __shfl_xor(sq2[nf], off, 64);
        }
    }
    if (lane < 16) {
        #pragma unroll
        for (int nf = 0; nf < 4; ++nf) {
            ps[wm][wn * 64 + nf * 16 + lane] = s[nf];
            pss2[wm][wn * 64 + nf * 16 + lane] = sq2[nf];
        }
    }
    __syncthreads();
    if (threadIdx.x < 128) {
        const size_t o = (size_t)blockIdx.x * 1024 + blockIdx.y * 128 + threadIdx.x;
        ops[o]  = ps[0][threadIdx.x] + ps[1][threadIdx.x];
        opss[o] = pss2[0][threadIdx.x] + pss2[1][threadIdx.x];
    }
}

// ---------- stats final (gl2) + pooled zero-init ----------
__global__ void stats_final_kernel(const float* __restrict__ psum, const float* __restrict__ psumsq,
                                   const float* __restrict__ g, const float* __restrict__ be,
                                   float* __restrict__ scale, float* __restrict__ shift,
                                   float* __restrict__ pooled,
                                   int C, int nchunks)
{
    const int c = blockIdx.x * 256 + threadIdx.x;
    if (c >= C) return;
    #pragma unroll
    for (int b = 0; b < 8; ++b) pooled[b * 1024 + c] = 0.f;
    float s = 0.f, ss = 0.f;
    for (int i = 0; i < nchunks; ++i) { s += psum[(size_t)i * C + c]; ss += psumsq[(size_t)i * C + c]; }
    const float invM = 1.f / (float)MROWS;
    const float mean = s * invM;
    const float var = fmaxf(ss * invM - mean * mean, 0.f);
    const float sc = g[c] * rsqrtf(var + 1e-5f);
    scale[c] = sc;
    shift[c] = be[c] - mean * sc;
}

// ---------- gather-max + folded BN-final, 64 ch ----------
__global__ __launch_bounds__(256)
void gathermax_bn64(const float* __restrict__ Hin, const int* __restrict__ idxmat,
                    const float* __restrict__ bps, const float* __restrict__ bpss,
                    const float* __restrict__ bg, const float* __restrict__ bbe,
                    float* __restrict__ Z)
{
    __shared__ float s_sc[64], s_sh[64];
    __shared__ float red[4][64], red2[4][64];
    const int tid = threadIdx.x;
    {
        const int c = tid & 63, part = tid >> 6;
        float s = 0.f, ss = 0.f;
        for (int i = part * 64; i < part * 64 + 64; ++i) {
            s += bps[(size_t)i * 64 + c]; ss += bpss[(size_t)i * 64 + c];
        }
        red[part][c] = s; red2[part][c] = ss;
        __syncthreads();
        if (tid < 64) {
            const float S  = red[0][tid] + red[1][tid] + red[2][tid] + red[3][tid];
            const float SS = red2[0][tid] + red2[1][tid] + red2[2][tid] + red2[3][tid];
            const float invM = 1.f / (float)MROWS;
            const float mean = S * invM;
            const float var = fmaxf(SS * invM - mean * mean, 0.f);
            const float sc = bg[tid] * rsqrtf(var + 1e-5f);
            s_sc[tid] = sc; s_sh[tid] = bbe[tid] - mean * sc;
        }
        __syncthreads();
    }
    const int c4 = tid & 15, rr = tid >> 4;
    const float4 sc = *(const float4*)&s_sc[c4 * 4];
    const float4 sh = *(const float4*)&s_sh[c4 * 4];
    #pragma unroll
    for (int it = 0; it < 4; ++it) {
        const int row = (blockIdx.x << 6) + (it << 4) + rr;
        const int* ip = idxmat + (size_t)row * KNN;
        float4 m = {0.f, 0.f, 0.f, 0.f};
        #pragma unroll
        for (int k = 0; k < KNN; ++k) {
            const int j = ip[k];
            const float4 v = *(const float4*)(Hin + (size_t)j * 64 + c4 * 4);
            m.x = fmaxf(m.x, fmaf(v.x, sc.x, sh.x));
            m.y = fmaxf(m.y, fmaf(v.y, sc.y, sh.y));
            m.z = fmaxf(m.z, fmaf(v.z, sc.z, sh.z));
            m.w = fmaxf(m.w, fmaf(v.w, sc.w, sh.w));
        }
        ((float4*)(Z + (size_t)row * 64))[c4] = m;
    }
}

// ---------- gather-max + folded BN-final, 128 ch, split-bf16 out ----------
__global__ __launch_bounds__(256)
void gathermax_bn128_split(const float* __restrict__ Hin, const int* __restrict__ idxmat,
                           const float* __restrict__ bps, const float* __restrict__ bpss,
                           const float* __restrict__ bg, const float* __restrict__ bbe,
                           unsigned short* __restrict__ Zhi, unsigned short* __restrict__ Zlo)
{
    __shared__ float s_sc[128], s_sh[128];
    __shared__ float red[2][128], red2[2][128];
    const int tid = threadIdx.x;
    {
        const int c = tid & 127, part = tid >> 7;
        float s = 0.f, ss = 0.f;
        for (int i = part * 128; i < part * 128 + 128; ++i) {
            s += bps[(size_t)i * 128 + c]; ss += bpss[(size_t)i * 128 + c];
        }
        red[part][c] = s; red2[part][c] = ss;
        __syncthreads();
        if (tid < 128) {
            const float S  = red[0][tid] + red[1][tid];
            const float SS = red2[0][tid] + red2[1][tid];
            const float invM = 1.f / (float)MROWS;
            const float mean = S * invM;
            const float var = fmaxf(SS * invM - mean * mean, 0.f);
            const float sc = bg[tid] * rsqrtf(var + 1e-5f);
            s_sc[tid] = sc; s_sh[tid] = bbe[tid] - mean * sc;
        }
        __syncthreads();
    }
    const int c4 = tid & 31, rr = tid >> 5;
    const float4 sc = *(const float4*)&s_sc[c4 * 4];
    const float4 sh = *(const float4*)&s_sh[c4 * 4];
    #pragma unroll
    for (int it = 0; it < 8; ++it) {
        const int row = (blockIdx.x << 6) + (it << 3) + rr;
        const int* ip = idxmat + (size_t)row * KNN;
        float4 m = {0.f, 0.f, 0.f, 0.f};
        #pragma unroll
        for (int k = 0; k < KNN; ++k) {
            const int j = ip[k];
            const float4 v = *(const float4*)(Hin + (size_t)j * 128 + c4 * 4);
            m.x = fmaxf(m.x, fmaf(v.x, sc.x, sh.x));
            m.y = fmaxf(m.y, fmaf(v.y, sc.y, sh.y));
            m.z = fmaxf(m.z, fmaf(v.z, sc.z, sh.z));
            m.w = fmaxf(m.w, fmaf(v.w, sc.w, sh.w));
        }
        ushort4 hi, lo;
        hi.x = f2bf(m.x); lo.x = f2bf(m.x - bf2f(hi.x));
        hi.y = f2bf(m.y); lo.y = f2bf(m.y - bf2f(hi.y));
        hi.z = f2bf(m.z); lo.z = f2bf(m.z - bf2f(hi.z));
        hi.w = f2bf(m.w); lo.w = f2bf(m.w - bf2f(hi.w));
        *(ushort4*)(Zhi + (size_t)row * 128 + c4 * 4) = hi;
        *(ushort4*)(Zlo + (size_t)row * 128 + c4 * 4) = lo;
    }
}

// ---------- fused bnrelu + masked segment max, fp32 ----------
__global__ __launch_bounds__(256)
void segmax_bnrelu_f32(const float* __restrict__ Y, const float* __restrict__ scale,
                       const float* __restrict__ shift, const int* __restrict__ mask,
                       unsigned* __restrict__ pooled)
{
    __shared__ int mk[64];
    const int b = blockIdx.x, nc = blockIdx.y;
    const int n0 = nc * 64;
    if (threadIdx.x < 64) mk[threadIdx.x] = mask[b * NPTS + n0 + threadIdx.x];
    __syncthreads();
    const int c4 = threadIdx.x;
    const float4 sc = ((const float4*)scale)[c4], sh = ((const float4*)shift)[c4];
    float4 m = {0.f, 0.f, 0.f, 0.f};
    for (int n = 0; n < 64; ++n) {
        if (mk[n]) {
            const float4 v = ((const float4*)(Y + ((size_t)b * NPTS + n0 + n) * 1024))[c4];
            m.x = fmaxf(m.x, fmaf(v.x, sc.x, sh.x));
            m.y = fmaxf(m.y, fmaf(v.y, sc.y, sh.y));
            m.z = fmaxf(m.z, fmaf(v.z, sc.z, sh.z));
            m.w = fmaxf(m.w, fmaf(v.w, sc.w, sh.w));
        }
    }
    m.x = fmaxf(m.x, 0.f); m.y = fmaxf(m.y, 0.f); m.z = fmaxf(m.z, 0.f); m.w = fmaxf(m.w, 0.f);
    atomicMax(&pooled[b * 1024 + c4 * 4 + 0], __float_as_uint(m.x));
    atomicMax(&pooled[b * 1024 + c4 * 4 + 1], __float_as_uint(m.y));
    atomicMax(&pooled[b * 1024 + c4 * 4 + 2], __float_as_uint(m.z));
    atomicMax(&pooled[b * 1024 + c4 * 4 + 3], __float_as_uint(m.w));
}

// ---------- head: 8-row GEMM + BN(8) + ReLU; 64 blocks x 8 cols, 32-way K-split ----------
template<int KDIM>
__global__ __launch_bounds__(256)
void mlp8_kernel(const float* __restrict__ In, const float* __restrict__ W,
                 const float* __restrict__ bias, const float* __restrict__ g,
                 const float* __restrict__ be, float* __restrict__ Out)
{
    __shared__ float Ins[8 * KDIM];
    __shared__ float part[32][8][8];
    __shared__ float ys[8][8];
    const int tid = threadIdx.x;
    for (int e = tid; e < 8 * KDIM; e += 256) Ins[e] = In[e];
    __syncthreads();
    const int c = tid & 7, kp = tid >> 3;      // 8 cols x 32 k-parts
    const int col = (blockIdx.x << 3) + c;
    constexpr int KS = KDIM / 32;
    float a[8] = {};
    for (int k = kp * KS; k < (kp + 1) * KS; ++k) {
        const float w = W[(size_t)k * 512 + col];
        #pragma unroll
        for (int r = 0; r < 8; ++r) a[r] = fmaf(Ins[r * KDIM + k], w, a[r]);
    }
    #pragma unroll
    for (int r = 0; r < 8; ++r) part[kp][r][c] = a[r];
    __syncthreads();
    if (tid < 64) {
        const int r = tid >> 3, cc = tid & 7;
        float s = 0.f;
        #pragma unroll
        for (int p = 0; p < 32; ++p) s += part[p][r][cc];
        ys[r][cc] = s + bias[(blockIdx.x << 3) + cc];
    }
    __syncthreads();
    if (tid < 8) {
        const int c2 = (blockIdx.x << 3) + tid;
        float s = 0.f, ss = 0.f;
        #pragma unroll
        for (int r = 0; r < 8; ++r) { const float v = ys[r][tid]; s += v; ss = fmaf(v, v, ss); }
        const float mean = s * 0.125f;
        const float var = fmaxf(ss * 0.125f - mean * mean, 0.f);
        const float sc = g[c2] * rsqrtf(var + 1e-5f);
        const float sh = be[c2] - mean * sc;
        #pragma unroll
        for (int r = 0; r < 8; ++r)
            Out[r * 512 + c2] = fmaxf(0.f, fmaf(ys[r][tid], sc, sh));
    }
}

// ---------- launcher ----------
extern "C" void kernel_launch(void* const* d_in, const int* in_sizes, int n_in,
                              void* d_out, int out_size, void* d_ws, size_t ws_size,
                              hipStream_t stream)
{
    const float* x    = (const float*)d_in[0];
    const int*   mask = (const int*)d_in[1];
    const float* w_m1a = (const float*)d_in[2];
    const float* b_m1a = (const float*)d_in[3];
    const float* g_m1a = (const float*)d_in[4];
    const float* be_m1a = (const float*)d_in[5];
    const float* w_m1b = (const float*)d_in[6];
    const float* b_m1b = (const float*)d_in[7];
    const float* g_m1b = (const float*)d_in[8];
    const float* be_m1b = (const float*)d_in[9];
    const float* w_m1c = (const float*)d_in[10];
    const float* b_m1c = (const float*)d_in[11];
    const float* g_m1c = (const float*)d_in[12];
    const float* be_m1c = (const float*)d_in[13];
    const float* w_gl1 = (const float*)d_in[14];
    const float* b_gl1 = (const float*)d_in[15];
    const float* g_gl1 = (const float*)d_in[16];
    const float* be_gl1 = (const float*)d_in[17];
    const float* w_gl2 = (const float*)d_in[18];
    const float* b_gl2 = (const float*)d_in[19];
    const float* g_gl2 = (const float*)d_in[20];
    const float* be_gl2 = (const float*)d_in[21];
    const float* w_m2a = (const float*)d_in[22];
    const float* b_m2a = (const float*)d_in[23];
    const float* g_m2a = (const float*)d_in[24];
    const float* be_m2a = (const float*)d_in[25];
    const float* w_m2b = (const float*)d_in[26];
    const float* b_m2b = (const float*)d_in[27];
    const float* g_m2b = (const float*)d_in[28];
    const float* be_m2b = (const float*)d_in[29];

    float* ws = (float*)d_ws;
    int*   idx  = (int*)ws;                              // +262144
    float* h0   = ws + 262144;                           // +196608
    float* bufA = ws + 458752;                           // +1048576
    float* bufB = ws + 1507328;                          // +1048576
    float* bufC = ws + 2555904;                          // +2097152
    unsigned short* wTh = (unsigned short*)(ws + 4653056);   // +65536
    unsigned short* wTl = (unsigned short*)(ws + 4718592);   // +65536
    float* bufE  = ws + 4784128;                         // +16777216
    float* pooled = ws + 21561344;                       // +8192
    float* y1     = ws + 21569536;                       // +4096
    float* ps0    = ws + 21573632;                       // +131072
    float* pss0   = ws + 21704704;                       // +131072
    float* ps1    = ws + 21835776;                       // +131072
    float* pss1   = ws + 21966848;                       // +131072
    float* scale  = ws + 22097920;                       // +1024
    float* shift  = ws + 22098944;                       // +1024

    unsigned short* Ahi = (unsigned short*)bufA;
    unsigned short* Alo = (unsigned short*)bufB;

    // knn + folded w_gl2 conversion
    knn_cov_kernel<<<4608, 256, 0, stream>>>(x, mask, idx, h0, w_gl2, wTh, wTl);

    // m1a: 12 -> 64 (writes stats chunks to ps0)
    gemm_bias_kernel<false><<<dim3(256, 1), 256, 0, stream>>>(
        h0, w_m1a, b_m1a, nullptr, nullptr, nullptr, nullptr, bufA, ps0, pss0, 12, 64);
    // m1b: 64 -> 64 (folds bn_m1a from ps0; writes ps1)
    gemm_bias_kernel<true><<<dim3(256, 1), 256, 0, stream>>>(
        bufA, w_m1b, b_m1b, ps0, pss0, g_m1a, be_m1a, bufB, ps1, pss1, 64, 64);
    // m1c: 64 -> 64 (folds bn_m1b from ps1; writes ps0)
    gemm_bias_kernel<true><<<dim3(256, 1), 256, 0, stream>>>(
        bufB, w_m1c, b_m1c, ps1, pss1, g_m1b, be_m1b, bufA, ps0, pss0, 64, 64);

    // gather-max 64 (folds bn_m1c from ps0)
    gathermax_bn64<<<256, 256, 0, stream>>>(bufA, idx, ps0, pss0, g_m1c, be_m1c, bufB);

    // gl1: 64 -> 128 (writes ps1)
    gemm_bias_kernel<false><<<dim3(256, 2), 256, 0, stream>>>(
        bufB, w_gl1, b_gl1, nullptr, nullptr, nullptr, nullptr, bufC, ps1, pss1, 64, 128);

    // gather-max 128 (folds bn_gl1 from ps1) -> split-bf16 A
    gathermax_bn128_split<<<256, 256, 0, stream>>>(bufC, idx, ps1, pss1, g_gl1, be_gl1, Ahi, Alo);

    // gl2: 128 -> 1024, split-bf16 MFMA + fused stats chunks
    gemm_gl2_mfma<<<dim3(128, 8), 256, 0, stream>>>(Ahi, Alo, wTh, wTl, b_gl2, bufE, ps0, pss0);
    stats_final_kernel<<<4, 256, 0, stream>>>(ps0, pss0, g_gl2, be_gl2, scale, shift, pooled, 1024, 128);

    // fused bnrelu + masked segment-max
    segmax_bnrelu_f32<<<dim3(8, 32), 256, 0, stream>>>(bufE, scale, shift, mask, (unsigned*)pooled);

    // head
    mlp8_kernel<1024><<<64, 256, 0, stream>>>(pooled, w_m2a, b_m2a, g_m2a, be_m2a, y1);
    mlp8_kernel<512><<<64, 256, 0, stream>>>(y1, w_m2b, b_m2b, g_m2b, be_m2b, (float*)d_out);
}